// Round 8
// baseline (239.682 us; speedup 1.0000x reference)
//
#include <hip/hip_runtime.h>

#define N_NODES 50000
#define N_EDGES 800000

typedef float f2 __attribute__((ext_vector_type(2)));

// DPP controls: quad_perm xor1=[1,0,3,2]=0xB1, xor2=[2,3,0,1]=0x4E,
// quad broadcasts, row_ror:4=0x124, row_ror:8=0x128
#define QX1 0xB1
#define QX2 0x4E
#define RR4 0x124
#define RR8 0x128
#define QB0 0x00
#define QB1 0x55
#define QB2 0xAA
#define QB3 0xFF

template <int CTRL>
__device__ __forceinline__ float dpp_add(float x) {
    int xi = __float_as_int(x);
    int yi = __builtin_amdgcn_update_dpp(xi, xi, CTRL, 0xF, 0xF, false);
    return x + __int_as_float(yi);
}
template <int CTRL>
__device__ __forceinline__ float dpp_max(float x) {
    int xi = __float_as_int(x);
    int yi = __builtin_amdgcn_update_dpp(xi, xi, CTRL, 0xF, 0xF, false);
    return fmaxf(x, __int_as_float(yi));
}
template <int CTRL>
__device__ __forceinline__ float dpp_mov(float x) {
    int xi = __float_as_int(x);
    return __int_as_float(__builtin_amdgcn_update_dpp(xi, xi, CTRL, 0xF, 0xF, false));
}

// per-lane 2-channel logit contribution; atv pre-scaled by log2e
__device__ __forceinline__ float logit2(f2 A, f2 xri, f2 atv) {
    f2 u = A + xri;
    f2 l = __builtin_elementwise_max(u, 0.2f * u);
    f2 d = l * atv;
    return d.x + d.y;
}

// pack 4 per-edge partials to lane bits 0,1 and sum over the 32-lane half.
__device__ __forceinline__ float quadtree(float t0, float t1, float t2, float t3, int lane) {
    t0 = dpp_add<QX1>(t0);
    t1 = dpp_add<QX1>(t1);
    t2 = dpp_add<QX1>(t2);
    t3 = dpp_add<QX1>(t3);
    float a = (lane & 1) ? t1 : t0;
    float b = (lane & 1) ? t3 : t2;
    a = dpp_add<QX2>(a);
    b = dpp_add<QX2>(b);
    float p = (lane & 2) ? b : a;
    p = dpp_add<RR4>(p);
    p = dpp_add<RR8>(p);
    p += __shfl_xor(p, 16);
    return p;
}

// ---------------- CSR build (single atomic pass + rank) ----------------
__global__ void k_hist(const int* __restrict__ dst, int* __restrict__ cnt,
                       unsigned short* __restrict__ rank, int E) {
    int e = blockIdx.x * blockDim.x + threadIdx.x;
    if (e < E) rank[e] = (unsigned short)atomicAdd(&cnt[dst[e]], 1);
}

__global__ void k_scan_local(const int* __restrict__ cnt, int* __restrict__ ptr,
                             int* __restrict__ bs, int n) {
    __shared__ int tmp[256];
    int t = threadIdx.x;
    int i = blockIdx.x * 256 + t;
    int v = (i < n) ? cnt[i] : 0;
    tmp[t] = v;
    __syncthreads();
    for (int d = 1; d < 256; d <<= 1) {
        int add = (t >= d) ? tmp[t - d] : 0;
        __syncthreads();
        tmp[t] += add;
        __syncthreads();
    }
    if (i < n) ptr[i] = tmp[t] - v;
    if (t == 255) bs[blockIdx.x] = tmp[255];
}

__global__ void k_scan_add2(int* __restrict__ ptr, const int* __restrict__ bs,
                            int n, int nbk, int E) {
    __shared__ int sh[256];
    int t = threadIdx.x;
    sh[t] = (t < nbk && t < blockIdx.x) ? bs[t] : 0;
    __syncthreads();
    for (int d = 128; d; d >>= 1) {
        if (t < d) sh[t] += sh[t + d];
        __syncthreads();
    }
    const int off = sh[0];
    int i = blockIdx.x * 256 + t;
    if (i < n) ptr[i] += off;
    if (i == 0) ptr[n] = E;
}

__global__ void k_scatter(const int* __restrict__ src, const int* __restrict__ dst,
                          const int* __restrict__ ptr, const unsigned short* __restrict__ rank,
                          int* __restrict__ csrc, int E) {
    int e = blockIdx.x * blockDim.x + threadIdx.x;
    if (e < E) csrc[ptr[dst[e]] + rank[e]] = src[e];
}

// ---------------- GEMM: 128x128 register-tiled, K=128 ----------------
template <bool WIDE>
__global__ __launch_bounds__(256)
void k_gemm_v2(const float* __restrict__ X, int nrows,
               const float* __restrict__ W0, const float* __restrict__ W1,
               float* __restrict__ Y0, float* __restrict__ Y1) {
    constexpr int BK = 32;
    __shared__ float xsT[BK][132];
    __shared__ float ws[BK][128];
    const int t = threadIdx.x;
    const int tx = t & 15, ty = t >> 4;
    const int row0 = blockIdx.x * 128;

    const float* Wa;
    const float* Wb;
    int ldw;
    float* Ya;
    float* Yb;
    if (WIDE) {
        const float* W = blockIdx.y ? W1 : W0;
        Wa = W;
        Wb = W + 64;
        ldw = 128;
        Ya = blockIdx.y ? Y1 : Y0;
        Yb = nullptr;
    } else {
        Wa = W0;
        Wb = W1;
        ldw = 64;
        Ya = Y0;
        Yb = Y1;
    }

    float acc[8][8] = {};

    for (int kc = 0; kc < 128; kc += BK) {
        __syncthreads();
        {
            const int row = t & 127;
            const int rg = min(row0 + row, nrows - 1);
            const float* xr = &X[(size_t)rg * 128 + kc];
#pragma unroll
            for (int i = 0; i < 4; ++i) {
                const int k0 = ((t >> 7) + 2 * i) * 4;
                float4 v = *(const float4*)&xr[k0];
                xsT[k0 + 0][row] = v.x;
                xsT[k0 + 1][row] = v.y;
                xsT[k0 + 2][row] = v.z;
                xsT[k0 + 3][row] = v.w;
            }
        }
#pragma unroll
        for (int i = 0; i < 4; ++i) {
            const int f4 = t + i * 256;
            const int k = f4 >> 5;
            const int c4 = (f4 & 31) * 4;
            const float* Wsrc = (c4 < 64) ? Wa : Wb;
            const int cc = (c4 < 64) ? c4 : c4 - 64;
            *(float4*)&ws[k][c4] = *(const float4*)&Wsrc[(size_t)(kc + k) * ldw + cc];
        }
        __syncthreads();
#pragma unroll 4
        for (int k = 0; k < BK; ++k) {
            const float4 a0 = *(const float4*)&xsT[k][ty * 4];
            const float4 a1 = *(const float4*)&xsT[k][ty * 4 + 64];
            const float4 b0 = *(const float4*)&ws[k][tx * 4];
            const float4 b1 = *(const float4*)&ws[k][tx * 4 + 64];
            const float ar[8] = {a0.x, a0.y, a0.z, a0.w, a1.x, a1.y, a1.z, a1.w};
            const float br[8] = {b0.x, b0.y, b0.z, b0.w, b1.x, b1.y, b1.z, b1.w};
#pragma unroll
            for (int i = 0; i < 8; ++i)
#pragma unroll
                for (int j = 0; j < 8; ++j)
                    acc[i][j] = fmaf(ar[i], br[j], acc[i][j]);
        }
    }

#pragma unroll
    for (int i = 0; i < 8; ++i) {
        const int r = row0 + ty * 4 + (i & 3) + (i >> 2) * 64;
        if (r >= nrows) continue;
        if (WIDE) {
            *(float4*)&Ya[(size_t)r * 128 + tx * 4] =
                make_float4(acc[i][0], acc[i][1], acc[i][2], acc[i][3]);
            *(float4*)&Ya[(size_t)r * 128 + 64 + tx * 4] =
                make_float4(acc[i][4], acc[i][5], acc[i][6], acc[i][7]);
        } else {
            *(float4*)&Ya[(size_t)r * 64 + tx * 4] =
                make_float4(acc[i][0], acc[i][1], acc[i][2], acc[i][3]);
            *(float4*)&Yb[(size_t)r * 64 + tx * 4] =
                make_float4(acc[i][4], acc[i][5], acc[i][6], acc[i][7]);
        }
    }
}

// ======== shared 8-edge compute step (merge of 8 edges into m/s/acc) ========
#define COMPUTE8(P, kk)                                                      \
    {                                                                        \
        const float t0 = logit2(P##0, xri, atv);                             \
        const float t1 = logit2(P##1, xri, atv);                             \
        const float t2 = logit2(P##2, xri, atv);                             \
        const float t3 = logit2(P##3, xri, atv);                             \
        const float t4 = logit2(P##4, xri, atv);                             \
        const float t5 = logit2(P##5, xri, atv);                             \
        const float t6 = logit2(P##6, xri, atv);                             \
        const float t7 = logit2(P##7, xri, atv);                             \
        float pA = quadtree(t0, t1, t2, t3, lane);                           \
        float pB = quadtree(t4, t5, t6, t7, lane);                           \
        pA = ((kk) + lane3 < nb4) ? pA : -1e30f;                             \
        pB = ((kk) + 4 + lane3 < nb4) ? pB : -1e30f;                         \
        float q = fmaxf(pA, pB);                                             \
        q = dpp_max<QX1>(q);                                                 \
        q = dpp_max<QX2>(q);                                                 \
        const float nm = fmaxf(m, q);                                        \
        const float sc = __builtin_amdgcn_exp2f(m - nm);                     \
        const float wA = __builtin_amdgcn_exp2f(pA - nm);                    \
        const float wB = __builtin_amdgcn_exp2f(pB - nm);                    \
        float sw = wA + wB;                                                  \
        sw = dpp_add<QX1>(sw);                                               \
        sw = dpp_add<QX2>(sw);                                               \
        s = fmaf(s, sc, sw);                                                 \
        m = nm;                                                              \
        const float w0 = dpp_mov<QB0>(wA), w1 = dpp_mov<QB1>(wA);            \
        const float w2 = dpp_mov<QB2>(wA), w3 = dpp_mov<QB3>(wA);            \
        const float w4 = dpp_mov<QB0>(wB), w5 = dpp_mov<QB1>(wB);            \
        const float w6 = dpp_mov<QB2>(wB), w7 = dpp_mov<QB3>(wB);            \
        acc = acc * sc;                                                      \
        acc += P##0 * w0;                                                    \
        acc += P##1 * w1;                                                    \
        acc += P##2 * w2;                                                    \
        acc += P##3 * w3;                                                    \
        acc += P##4 * w4;                                                    \
        acc += P##5 * w5;                                                    \
        acc += P##6 * w6;                                                    \
        acc += P##7 * w7;                                                    \
    }

// double-buffered chunk loop: issue next set's gathers before current compute
#define CHUNK_LOOP(LOADM)                                                    \
    for (int k = 0; k < nb4; k += 16) {                                      \
        const bool hasB = (k + 8 < nb4);                                     \
        if (hasB) LOADM(B, k + 8);                                           \
        COMPUTE8(A, k);                                                      \
        if (hasB) {                                                          \
            if (k + 16 < nb4) LOADM(A, k + 16);                              \
            COMPUTE8(B, k + 8);                                              \
        }                                                                    \
    }

// ---------------- layer-1 fused GATv2 aggregation ([N][128]) ----------------
// lane l: channels 2l,2l+1 of head (l>>5). Double-buffered 8-edge gather sets.
#define LOAD8_1(P, kk)                                                       \
    {                                                                        \
        const int c = nb4 - 1;                                               \
        const int j0 = __builtin_amdgcn_readlane(idx, min((kk) + 0, c));     \
        const int j1 = __builtin_amdgcn_readlane(idx, min((kk) + 1, c));     \
        const int j2 = __builtin_amdgcn_readlane(idx, min((kk) + 2, c));     \
        const int j3 = __builtin_amdgcn_readlane(idx, min((kk) + 3, c));     \
        const int j4 = __builtin_amdgcn_readlane(idx, min((kk) + 4, c));     \
        const int j5 = __builtin_amdgcn_readlane(idx, min((kk) + 5, c));     \
        const int j6 = __builtin_amdgcn_readlane(idx, min((kk) + 6, c));     \
        const int j7 = __builtin_amdgcn_readlane(idx, min((kk) + 7, c));     \
        P##0 = *(const f2*)(xl + ((size_t)j0 << 7) + 2 * lane);              \
        P##1 = *(const f2*)(xl + ((size_t)j1 << 7) + 2 * lane);              \
        P##2 = *(const f2*)(xl + ((size_t)j2 << 7) + 2 * lane);              \
        P##3 = *(const f2*)(xl + ((size_t)j3 << 7) + 2 * lane);              \
        P##4 = *(const f2*)(xl + ((size_t)j4 << 7) + 2 * lane);              \
        P##5 = *(const f2*)(xl + ((size_t)j5 << 7) + 2 * lane);              \
        P##6 = *(const f2*)(xl + ((size_t)j6 << 7) + 2 * lane);              \
        P##7 = *(const f2*)(xl + ((size_t)j7 << 7) + 2 * lane);              \
    }

__global__ __launch_bounds__(256) void k_agg1(
    const float* __restrict__ xl, const float* __restrict__ xr,
    const float* __restrict__ att, const float* __restrict__ bias,
    const int* __restrict__ ptr, const int* __restrict__ csrc,
    float* __restrict__ out) {
    const int node = blockIdx.x * 4 + (threadIdx.x >> 6);
    const int lane = threadIdx.x & 63;
    if (node >= N_NODES) return;
    const size_t nb = (size_t)node * 128;
    const f2 xri = *(const f2*)&xr[nb + 2 * lane];
    f2 atv = *(const f2*)&att[2 * lane];
    atv *= 1.44269504088896340736f;  // log2(e): softmax in exp2 domain
    const int lane3 = lane & 3;

    const int e0 = ptr[node];
    const int deg = ptr[node + 1] - e0;

    f2 A0, A1, A2, A3, A4, A5, A6, A7;
    f2 B0, B1, B2, B3, B4, B5, B6, B7;

    // chunk-0 prologue: issue idx load + first gather set BEFORE self-loop math
    int nv = deg;
    int nb4 = min(nv, 64);
    int idx = 0;
    if (deg > 0) {
        idx = csrc[e0 + min(lane, nv - 1)];
        LOAD8_1(A, 0);
    }

    // self loop (overlaps with in-flight gathers)
    const f2 xs = *(const f2*)&xl[nb + 2 * lane];
    f2 acc;
    float m, s;
    {
        float t = logit2(xs, xri, atv);
        t = dpp_add<QX1>(t);
        t = dpp_add<QX2>(t);
        t = dpp_add<RR4>(t);
        t = dpp_add<RR8>(t);
        t += __shfl_xor(t, 16);
        m = t;
        s = 1.0f;
        acc = xs;
    }

    if (deg > 0) {
        CHUNK_LOOP(LOAD8_1)
    }
    for (int base = 64; base < deg; base += 64) {  // rare: deg > 64
        nv = deg - base;
        nb4 = min(nv, 64);
        idx = csrc[e0 + base + min(lane, nv - 1)];
        LOAD8_1(A, 0);
        CHUNK_LOOP(LOAD8_1)
    }

    const float inv = 1.0f / s;
    const f2 bv = *(const f2*)&bias[2 * lane];
    f2 o = acc * inv + bv;
    o = __builtin_elementwise_max(o, (f2)(0.0f));
    *(f2*)&out[nb + 2 * lane] = o;
}

// ---------------- layer-2 aggregation + fused FC head ----------------
// 2 nodes per wave (lanes 0-31 / 32-63); lane holds channels 2*(l&31), +1.
#define LOAD8_2(P, kk)                                                       \
    {                                                                        \
        const int bb = ((lane & 32) + (kk)) << 2;                            \
        const int j0 = __builtin_amdgcn_ds_bpermute(bb + 0, idx);            \
        const int j1 = __builtin_amdgcn_ds_bpermute(bb + 4, idx);            \
        const int j2 = __builtin_amdgcn_ds_bpermute(bb + 8, idx);            \
        const int j3 = __builtin_amdgcn_ds_bpermute(bb + 12, idx);           \
        const int j4 = __builtin_amdgcn_ds_bpermute(bb + 16, idx);           \
        const int j5 = __builtin_amdgcn_ds_bpermute(bb + 20, idx);           \
        const int j6 = __builtin_amdgcn_ds_bpermute(bb + 24, idx);           \
        const int j7 = __builtin_amdgcn_ds_bpermute(bb + 28, idx);           \
        P##0 = *(const f2*)(xl + (((unsigned)j0) << 6) + 2 * hl);            \
        P##1 = *(const f2*)(xl + (((unsigned)j1) << 6) + 2 * hl);            \
        P##2 = *(const f2*)(xl + (((unsigned)j2) << 6) + 2 * hl);            \
        P##3 = *(const f2*)(xl + (((unsigned)j3) << 6) + 2 * hl);            \
        P##4 = *(const f2*)(xl + (((unsigned)j4) << 6) + 2 * hl);            \
        P##5 = *(const f2*)(xl + (((unsigned)j5) << 6) + 2 * hl);            \
        P##6 = *(const f2*)(xl + (((unsigned)j6) << 6) + 2 * hl);            \
        P##7 = *(const f2*)(xl + (((unsigned)j7) << 6) + 2 * hl);            \
    }

__global__ __launch_bounds__(256) void k_agg2_fc(
    const float* __restrict__ xl, const float* __restrict__ xr,
    const float* __restrict__ att, const float* __restrict__ bias,
    const int* __restrict__ ptr, const int* __restrict__ csrc,
    const float* __restrict__ Wfc, const float* __restrict__ bfc,
    float* __restrict__ out) {
    const int wid = blockIdx.x * 4 + (threadIdx.x >> 6);
    const int lane = threadIdx.x & 63;
    const int hl = lane & 31;
    const int node = wid * 2 + (lane >> 5);  // N even, grid exact
    const int lane3 = lane & 3;
    const size_t nbo = (size_t)node * 64;
    const f2 xri = *(const f2*)&xr[nbo + 2 * hl];
    f2 atv = *(const f2*)&att[2 * hl];
    atv *= 1.44269504088896340736f;

    const int e0 = ptr[node];
    const int deg = ptr[node + 1] - e0;
    const int degw = max(deg, __shfl_xor(deg, 32));

    f2 A0, A1, A2, A3, A4, A5, A6, A7;
    f2 B0, B1, B2, B3, B4, B5, B6, B7;

    // chunk-0 prologue before self-loop math
    int nv = deg;
    int nb4 = min(nv, 32);
    int idx = 0;
    if (degw > 0) {
        const int off = max(0, min(hl, nv - 1));
        idx = csrc[min(e0 + off, N_EDGES - 1)];
        LOAD8_2(A, 0);
    }

    const f2 xs = *(const f2*)&xl[nbo + 2 * hl];
    f2 acc;
    float m, s;
    {
        float t = logit2(xs, xri, atv);
        t = dpp_add<QX1>(t);
        t = dpp_add<QX2>(t);
        t = dpp_add<RR4>(t);
        t = dpp_add<RR8>(t);
        t += __shfl_xor(t, 16);
        m = t;
        s = 1.0f;
        acc = xs;
    }

    if (degw > 0) {
        const int kw = min(32, degw);
        for (int k = 0; k < kw; k += 16) {
            const bool hasB = (k + 8 < kw);
            if (hasB) LOAD8_2(B, k + 8);
            COMPUTE8(A, k);
            if (hasB) {
                if (k + 16 < kw) LOAD8_2(A, k + 16);
                COMPUTE8(B, k + 8);
            }
        }
    }
    for (int base = 32; base < degw; base += 32) {  // rare: degw > 32
        nv = deg - base;
        nb4 = min(nv, 32);
        const int off = max(0, min(hl, nv - 1));
        idx = csrc[min(e0 + base + off, N_EDGES - 1)];
        LOAD8_2(A, 0);
        const int kw = min(32, degw - base);
        for (int k = 0; k < kw; k += 16) {
            const bool hasB = (k + 8 < kw);
            if (hasB) LOAD8_2(B, k + 8);
            COMPUTE8(A, k);
            if (hasB) {
                if (k + 16 < kw) LOAD8_2(A, k + 16);
                COMPUTE8(B, k + 8);
            }
        }
    }

    const float inv = 1.0f / s;
    const float v0 = fmaxf(fmaf(acc.x, inv, bias[2 * hl]), 0.0f);
    const float v1 = fmaxf(fmaf(acc.y, inv, bias[2 * hl + 1]), 0.0f);

    // FC head: per group g, quad-pack tree -> class at lane bits 0,1
    float res = 0.0f;
#pragma unroll
    for (int g = 0; g < 3; ++g) {
        const int cb = 4 * g;
        const int c0 = cb, c1 = cb + 1;
        const int c2 = min(cb + 2, 9), c3 = min(cb + 3, 9);
        const float* w0r = &Wfc[(2 * hl) * 10];
        const float* w1r = &Wfc[(2 * hl + 1) * 10];
        float u0 = v0 * w0r[c0] + v1 * w1r[c0];
        float u1 = v0 * w0r[c1] + v1 * w1r[c1];
        float u2 = v0 * w0r[c2] + v1 * w1r[c2];
        float u3 = v0 * w0r[c3] + v1 * w1r[c3];
        const float t = quadtree(u0, u1, u2, u3, lane);
        if ((hl >> 2) == g) res = t;
    }
    if (hl < 10) out[(size_t)node * 10 + hl] = res + bfc[hl];
}

// ---------------- launch ----------------
static inline size_t align256(size_t x) { return (x + 255) & ~(size_t)255; }

extern "C" void kernel_launch(void* const* d_in, const int* in_sizes, int n_in,
                              void* d_out, int out_size, void* d_ws, size_t ws_size,
                              hipStream_t stream) {
    const int N = N_NODES, E = N_EDGES;
    const float* x    = (const float*)d_in[0];
    const int*   ei   = (const int*)d_in[1];
    const float* Wl1  = (const float*)d_in[2];
    const float* Wr1  = (const float*)d_in[3];
    const float* att1 = (const float*)d_in[4];
    const float* b1   = (const float*)d_in[5];
    const float* Wl2  = (const float*)d_in[6];
    const float* Wr2  = (const float*)d_in[7];
    const float* att2 = (const float*)d_in[8];
    const float* b2   = (const float*)d_in[9];
    const float* Wfc  = (const float*)d_in[10];
    const float* bfc  = (const float*)d_in[11];
    float* out = (float*)d_out;

    const int* src = ei;
    const int* dst = ei + E;

    char* base = (char*)d_ws;
    size_t off = 0;
    int* ptr  = (int*)(base + off); off = align256(off + (size_t)(N + 1) * 4);
    int* cnt  = (int*)(base + off); off = align256(off + (size_t)N * 4);
    int* bs   = (int*)(base + off); off = align256(off + 256 * 4);
    unsigned short* rank = (unsigned short*)(base + off); off = align256(off + (size_t)E * 2);
    int* csrc = (int*)(base + off); off = align256(off + (size_t)E * 4);
    float* xl1 = (float*)(base + off); off = align256(off + (size_t)N * 128 * 4);
    float* xr1 = (float*)(base + off); off = align256(off + (size_t)N * 128 * 4);
    float* h1  = (float*)(base + off); off = align256(off + (size_t)N * 128 * 4);
    float* xl2 = xl1;
    float* xr2 = xl1 + (size_t)N * 64;

    const int nb = (N + 255) / 256;
    const int ngb = (N + 127) / 128;

    hipMemsetAsync(cnt, 0, (size_t)N * 4, stream);
    k_hist<<<(E + 255) / 256, 256, 0, stream>>>(dst, cnt, rank, E);
    k_scan_local<<<nb, 256, 0, stream>>>(cnt, ptr, bs, N);
    k_scan_add2<<<nb, 256, 0, stream>>>(ptr, bs, N, nb, E);
    k_scatter<<<(E + 255) / 256, 256, 0, stream>>>(src, dst, ptr, rank, csrc, E);

    // layer 1: xl1/xr1 standard [N][128]
    k_gemm_v2<true><<<dim3(ngb, 2), 256, 0, stream>>>(x, N, Wl1, Wr1, xl1, xr1);
    k_agg1<<<(N + 3) / 4, 256, 0, stream>>>(xl1, xr1, att1, b1, ptr, csrc, h1);
    // layer 2: [N][64] x2
    k_gemm_v2<false><<<dim3(ngb, 1), 256, 0, stream>>>(h1, N, Wl2, Wr2, xl2, xr2);
    k_agg2_fc<<<(N / 2 + 3) / 4, 256, 0, stream>>>(xl2, xr2, att2, b2, ptr, csrc, Wfc, bfc, out);
}

// Round 9
// 225.207 us; speedup vs baseline: 1.0643x; 1.0643x over previous
//
#include <hip/hip_runtime.h>

#define N_NODES 50000
#define N_EDGES 800000

typedef float f2 __attribute__((ext_vector_type(2)));

// DPP controls: quad_perm xor1=0xB1, xor2=0x4E, row_ror:4=0x124, row_ror:8=0x128
#define QX1 0xB1
#define QX2 0x4E
#define RR4 0x124
#define RR8 0x128
#define QB0 0x00
#define QB1 0x55
#define QB2 0xAA
#define QB3 0xFF

template <int CTRL>
__device__ __forceinline__ float dpp_add(float x) {
    int xi = __float_as_int(x);
    int yi = __builtin_amdgcn_update_dpp(xi, xi, CTRL, 0xF, 0xF, false);
    return x + __int_as_float(yi);
}
template <int CTRL>
__device__ __forceinline__ float dpp_max(float x) {
    int xi = __float_as_int(x);
    int yi = __builtin_amdgcn_update_dpp(xi, xi, CTRL, 0xF, 0xF, false);
    return fmaxf(x, __int_as_float(yi));
}
template <int CTRL>
__device__ __forceinline__ float dpp_mov(float x) {
    int xi = __float_as_int(x);
    return __int_as_float(__builtin_amdgcn_update_dpp(xi, xi, CTRL, 0xF, 0xF, false));
}

__device__ __forceinline__ float lrelu(float x) { return fmaxf(x, 0.2f * x); }

// f32 -> bf16 round-to-nearest-even
__device__ __forceinline__ unsigned short f2bf(float x) {
    unsigned b = __float_as_uint(x);
    b += 0x7fffu + ((b >> 16) & 1u);
    return (unsigned short)(b >> 16);
}
// 4 bf16 (uint2) -> 2 f2
__device__ __forceinline__ void cvt4(uint2 u, f2& c01, f2& c23) {
    c01.x = __uint_as_float(u.x << 16);
    c01.y = __uint_as_float(u.x & 0xffff0000u);
    c23.x = __uint_as_float(u.y << 16);
    c23.y = __uint_as_float(u.y & 0xffff0000u);
}

// 4-channel logit contribution per lane (packed f32)
__device__ __forceinline__ float logit4(f2 c01, f2 c23, f2 xri01, f2 xri23, f2 atv01, f2 atv23) {
    f2 u0 = c01 + xri01, u1 = c23 + xri23;
    f2 l0 = __builtin_elementwise_max(u0, 0.2f * u0);
    f2 l1 = __builtin_elementwise_max(u1, 0.2f * u1);
    f2 d = l0 * atv01 + l1 * atv23;
    return d.x + d.y;
}

// sum over 16-lane row (all-DPP)
__device__ __forceinline__ float rsum16(float t) {
    t = dpp_add<QX1>(t);
    t = dpp_add<QX2>(t);
    t = dpp_add<RR4>(t);
    t = dpp_add<RR8>(t);
    return t;
}

// 2-channel logit (layer-2 path)
__device__ __forceinline__ float logit2(f2 A, f2 xri, f2 atv) {
    f2 u = A + xri;
    f2 l = __builtin_elementwise_max(u, 0.2f * u);
    f2 d = l * atv;
    return d.x + d.y;
}
__device__ __forceinline__ float quadtree(float t0, float t1, float t2, float t3, int lane) {
    t0 = dpp_add<QX1>(t0);
    t1 = dpp_add<QX1>(t1);
    t2 = dpp_add<QX1>(t2);
    t3 = dpp_add<QX1>(t3);
    float a = (lane & 1) ? t1 : t0;
    float b = (lane & 1) ? t3 : t2;
    a = dpp_add<QX2>(a);
    b = dpp_add<QX2>(b);
    float p = (lane & 2) ? b : a;
    p = dpp_add<RR4>(p);
    p = dpp_add<RR8>(p);
    p += __shfl_xor(p, 16);
    return p;
}

// ---------------- CSR build ----------------
__global__ void k_hist(const int* __restrict__ dst, int* __restrict__ cnt,
                       unsigned short* __restrict__ rank, int E) {
    int e = blockIdx.x * blockDim.x + threadIdx.x;
    if (e < E) rank[e] = (unsigned short)atomicAdd(&cnt[dst[e]], 1);
}

__global__ void k_scan_local(const int* __restrict__ cnt, int* __restrict__ ptr,
                             int* __restrict__ bs, int n) {
    __shared__ int tmp[256];
    int t = threadIdx.x;
    int i = blockIdx.x * 256 + t;
    int v = (i < n) ? cnt[i] : 0;
    tmp[t] = v;
    __syncthreads();
    for (int d = 1; d < 256; d <<= 1) {
        int add = (t >= d) ? tmp[t - d] : 0;
        __syncthreads();
        tmp[t] += add;
        __syncthreads();
    }
    if (i < n) ptr[i] = tmp[t] - v;
    if (t == 255) bs[blockIdx.x] = tmp[255];
}

__global__ void k_scan_add2(int* __restrict__ ptr, const int* __restrict__ bs,
                            int n, int nbk, int E) {
    __shared__ int sh[256];
    int t = threadIdx.x;
    sh[t] = (t < nbk && t < blockIdx.x) ? bs[t] : 0;
    __syncthreads();
    for (int d = 128; d; d >>= 1) {
        if (t < d) sh[t] += sh[t + d];
        __syncthreads();
    }
    const int off = sh[0];
    int i = blockIdx.x * 256 + t;
    if (i < n) ptr[i] += off;
    if (i == 0) ptr[n] = E;
}

__global__ void k_scatter(const int* __restrict__ src, const int* __restrict__ dst,
                          const int* __restrict__ ptr, const unsigned short* __restrict__ rank,
                          int* __restrict__ csrc, int E) {
    int e = blockIdx.x * blockDim.x + threadIdx.x;
    if (e < E) csrc[ptr[dst[e]] + rank[e]] = src[e];
}

// ---------------- GEMM: 128x128 register-tiled, K=128 ----------------
// WIDE: blockIdx.y==0 -> x@W0 stored as bf16 [N][128] into Y0 (reinterpreted);
//       blockIdx.y==1 -> x@W1 stored f32 [N][128] into Y1.
template <bool WIDE>
__global__ __launch_bounds__(256)
void k_gemm_v2(const float* __restrict__ X, int nrows,
               const float* __restrict__ W0, const float* __restrict__ W1,
               float* __restrict__ Y0, float* __restrict__ Y1) {
    constexpr int BK = 32;
    __shared__ float xsT[BK][132];
    __shared__ float ws[BK][128];
    const int t = threadIdx.x;
    const int tx = t & 15, ty = t >> 4;
    const int row0 = blockIdx.x * 128;

    const float* Wa;
    const float* Wb;
    int ldw;
    float* Ya;
    float* Yb;
    if (WIDE) {
        const float* W = blockIdx.y ? W1 : W0;
        Wa = W;
        Wb = W + 64;
        ldw = 128;
        Ya = blockIdx.y ? Y1 : Y0;
        Yb = nullptr;
    } else {
        Wa = W0;
        Wb = W1;
        ldw = 64;
        Ya = Y0;
        Yb = Y1;
    }

    float acc[8][8] = {};

    for (int kc = 0; kc < 128; kc += BK) {
        __syncthreads();
        {
            const int row = t & 127;
            const int rg = min(row0 + row, nrows - 1);
            const float* xr = &X[(size_t)rg * 128 + kc];
#pragma unroll
            for (int i = 0; i < 4; ++i) {
                const int k0 = ((t >> 7) + 2 * i) * 4;
                float4 v = *(const float4*)&xr[k0];
                xsT[k0 + 0][row] = v.x;
                xsT[k0 + 1][row] = v.y;
                xsT[k0 + 2][row] = v.z;
                xsT[k0 + 3][row] = v.w;
            }
        }
#pragma unroll
        for (int i = 0; i < 4; ++i) {
            const int f4 = t + i * 256;
            const int k = f4 >> 5;
            const int c4 = (f4 & 31) * 4;
            const float* Wsrc = (c4 < 64) ? Wa : Wb;
            const int cc = (c4 < 64) ? c4 : c4 - 64;
            *(float4*)&ws[k][c4] = *(const float4*)&Wsrc[(size_t)(kc + k) * ldw + cc];
        }
        __syncthreads();
#pragma unroll 4
        for (int k = 0; k < BK; ++k) {
            const float4 a0 = *(const float4*)&xsT[k][ty * 4];
            const float4 a1 = *(const float4*)&xsT[k][ty * 4 + 64];
            const float4 b0 = *(const float4*)&ws[k][tx * 4];
            const float4 b1 = *(const float4*)&ws[k][tx * 4 + 64];
            const float ar[8] = {a0.x, a0.y, a0.z, a0.w, a1.x, a1.y, a1.z, a1.w};
            const float br[8] = {b0.x, b0.y, b0.z, b0.w, b1.x, b1.y, b1.z, b1.w};
#pragma unroll
            for (int i = 0; i < 8; ++i)
#pragma unroll
                for (int j = 0; j < 8; ++j)
                    acc[i][j] = fmaf(ar[i], br[j], acc[i][j]);
        }
    }

#pragma unroll
    for (int i = 0; i < 8; ++i) {
        const int r = row0 + ty * 4 + (i & 3) + (i >> 2) * 64;
        if (r >= nrows) continue;
        if (WIDE) {
            if (blockIdx.y == 0) {
                unsigned short* Yh = (unsigned short*)Ya;
                uint2 ulo, uhi;
                ulo.x = (unsigned)f2bf(acc[i][0]) | ((unsigned)f2bf(acc[i][1]) << 16);
                ulo.y = (unsigned)f2bf(acc[i][2]) | ((unsigned)f2bf(acc[i][3]) << 16);
                uhi.x = (unsigned)f2bf(acc[i][4]) | ((unsigned)f2bf(acc[i][5]) << 16);
                uhi.y = (unsigned)f2bf(acc[i][6]) | ((unsigned)f2bf(acc[i][7]) << 16);
                *(uint2*)&Yh[(size_t)r * 128 + tx * 4] = ulo;
                *(uint2*)&Yh[(size_t)r * 128 + 64 + tx * 4] = uhi;
            } else {
                *(float4*)&Ya[(size_t)r * 128 + tx * 4] =
                    make_float4(acc[i][0], acc[i][1], acc[i][2], acc[i][3]);
                *(float4*)&Ya[(size_t)r * 128 + 64 + tx * 4] =
                    make_float4(acc[i][4], acc[i][5], acc[i][6], acc[i][7]);
            }
        } else {
            *(float4*)&Ya[(size_t)r * 64 + tx * 4] =
                make_float4(acc[i][0], acc[i][1], acc[i][2], acc[i][3]);
            *(float4*)&Yb[(size_t)r * 64 + tx * 4] =
                make_float4(acc[i][4], acc[i][5], acc[i][6], acc[i][7]);
        }
    }
}

// ---------------- layer-1 aggregation: bf16 table, 2 edges per load ----------------
// lane: hl=lane&31 -> channels 4hl..4hl+3 (head = hl>>4 = 16-lane row); half = lane>>5
// processes edges 2t+half. Per-half online softmax; cross-half merge at end.
#define LOAD1(P, TB)                                                              \
    {                                                                             \
        const int c_ = nsteps - 1;                                                \
        const int a0_ = (min((TB) + 0, c_) << 3) + h4;                            \
        const int a1_ = (min((TB) + 1, c_) << 3) + h4;                            \
        const int a2_ = (min((TB) + 2, c_) << 3) + h4;                            \
        const int a3_ = (min((TB) + 3, c_) << 3) + h4;                            \
        const int j0_ = __builtin_amdgcn_ds_bpermute(a0_, idx);                   \
        const int j1_ = __builtin_amdgcn_ds_bpermute(a1_, idx);                   \
        const int j2_ = __builtin_amdgcn_ds_bpermute(a2_, idx);                   \
        const int j3_ = __builtin_amdgcn_ds_bpermute(a3_, idx);                   \
        P##0 = *(const uint2*)(xlbB + (((unsigned)j0_ << 8) + h8));               \
        P##1 = *(const uint2*)(xlbB + (((unsigned)j1_ << 8) + h8));               \
        P##2 = *(const uint2*)(xlbB + (((unsigned)j2_ << 8) + h8));               \
        P##3 = *(const uint2*)(xlbB + (((unsigned)j3_ << 8) + h8));               \
    }

#define COMP1(P, TB)                                                              \
    {                                                                             \
        f2 c01_0, c23_0, c01_1, c23_1, c01_2, c23_2, c01_3, c23_3;                \
        cvt4(P##0, c01_0, c23_0);                                                 \
        cvt4(P##1, c01_1, c23_1);                                                 \
        cvt4(P##2, c01_2, c23_2);                                                 \
        cvt4(P##3, c01_3, c23_3);                                                 \
        float p0 = rsum16(logit4(c01_0, c23_0, xri01, xri23, atv01, atv23));      \
        float p1 = rsum16(logit4(c01_1, c23_1, xri01, xri23, atv01, atv23));      \
        float p2 = rsum16(logit4(c01_2, c23_2, xri01, xri23, atv01, atv23));      \
        float p3 = rsum16(logit4(c01_3, c23_3, xri01, xri23, atv01, atv23));      \
        const bool v0_ = 2 * ((TB) + 0) + hh < nb4;                               \
        const bool v1_ = 2 * ((TB) + 1) + hh < nb4;                               \
        const bool v2_ = 2 * ((TB) + 2) + hh < nb4;                               \
        const bool v3_ = 2 * ((TB) + 3) + hh < nb4;                               \
        p0 = v0_ ? p0 : -1e30f;                                                   \
        p1 = v1_ ? p1 : -1e30f;                                                   \
        p2 = v2_ ? p2 : -1e30f;                                                   \
        p3 = v3_ ? p3 : -1e30f;                                                   \
        const float q_ = fmaxf(fmaxf(p0, p1), fmaxf(p2, p3));                     \
        const float nm_ = fmaxf(m, q_);                                           \
        const float sc_ = __builtin_amdgcn_exp2f(m - nm_);                        \
        const float w0_ = v0_ ? __builtin_amdgcn_exp2f(p0 - nm_) : 0.0f;          \
        const float w1_ = v1_ ? __builtin_amdgcn_exp2f(p1 - nm_) : 0.0f;          \
        const float w2_ = v2_ ? __builtin_amdgcn_exp2f(p2 - nm_) : 0.0f;          \
        const float w3_ = v3_ ? __builtin_amdgcn_exp2f(p3 - nm_) : 0.0f;          \
        s = fmaf(s, sc_, (w0_ + w1_) + (w2_ + w3_));                              \
        m = nm_;                                                                  \
        acc01 = acc01 * sc_;                                                      \
        acc23 = acc23 * sc_;                                                      \
        acc01 += c01_0 * w0_;                                                     \
        acc23 += c23_0 * w0_;                                                     \
        acc01 += c01_1 * w1_;                                                     \
        acc23 += c23_1 * w1_;                                                     \
        acc01 += c01_2 * w2_;                                                     \
        acc23 += c23_2 * w2_;                                                     \
        acc01 += c01_3 * w3_;                                                     \
        acc23 += c23_3 * w3_;                                                     \
    }

__global__ __launch_bounds__(256) void k_agg1(
    const unsigned short* __restrict__ xlb, const float* __restrict__ xr,
    const float* __restrict__ att, const float* __restrict__ bias,
    const int* __restrict__ ptr, const int* __restrict__ csrc,
    float* __restrict__ out) {
    const int node = blockIdx.x * 4 + (threadIdx.x >> 6);
    const int lane = threadIdx.x & 63;
    if (node >= N_NODES) return;
    const int hl = lane & 31;
    const int hh = lane >> 5;
    const int h4 = hh << 2;
    const unsigned h8 = (unsigned)hl << 3;
    const char* xlbB = (const char*)xlb;
    const size_t cb = (size_t)node * 128 + 4 * hl;

    // issue independent loads first
    const int e0 = ptr[node];
    const int deg = ptr[node + 1] - e0;
    const uint2 su = *(const uint2*)(xlbB + (((unsigned)node << 8) + h8));
    const float4 xv = *(const float4*)&xr[cb];
    const float4 av = *(const float4*)&att[4 * hl];

    uint2 A0, A1, A2, A3, B0, B1, B2, B3;
    int nv = deg, nb4 = min(nv, 64), nsteps = (nb4 + 1) >> 1, idx = 0;
    if (deg > 0) {
        idx = csrc[e0 + min(lane, nv - 1)];
        LOAD1(A, 0);
        if (nsteps > 4) LOAD1(B, 4);
    }

    const f2 xri01 = {xv.x, xv.y}, xri23 = {xv.z, xv.w};
    const float l2e = 1.44269504088896340736f;
    const f2 atv01 = {av.x * l2e, av.y * l2e}, atv23 = {av.z * l2e, av.w * l2e};

    // self loop (half 0 only)
    f2 s01, s23;
    cvt4(su, s01, s23);
    const float ps = rsum16(logit4(s01, s23, xri01, xri23, atv01, atv23));
    float m = hh ? -1e30f : ps;
    float s = hh ? 0.0f : 1.0f;
    f2 acc01 = hh ? (f2)0.0f : s01;
    f2 acc23 = hh ? (f2)0.0f : s23;

    if (deg > 0) {
        for (int tb = 0; tb < nsteps; tb += 8) {
            COMP1(A, tb);
            if (tb + 4 < nsteps) {
                if (tb + 8 < nsteps) LOAD1(A, tb + 8);
                COMP1(B, tb + 4);
                if (tb + 12 < nsteps) LOAD1(B, tb + 12);
            }
        }
    }
    for (int base = 64; base < deg; base += 64) {  // rare: deg > 64
        nv = deg - base;
        nb4 = min(nv, 64);
        nsteps = (nb4 + 1) >> 1;
        idx = csrc[e0 + base + min(lane, nv - 1)];
        LOAD1(A, 0);
        if (nsteps > 4) LOAD1(B, 4);
        for (int tb = 0; tb < nsteps; tb += 8) {
            COMP1(A, tb);
            if (tb + 4 < nsteps) {
                if (tb + 8 < nsteps) LOAD1(A, tb + 8);
                COMP1(B, tb + 4);
                if (tb + 12 < nsteps) LOAD1(B, tb + 12);
            }
        }
    }

    // cross-half merge
    const float mo = __shfl_xor(m, 32);
    const float so = __shfl_xor(s, 32);
    f2 o01, o23;
    o01.x = __shfl_xor(acc01.x, 32);
    o01.y = __shfl_xor(acc01.y, 32);
    o23.x = __shfl_xor(acc23.x, 32);
    o23.y = __shfl_xor(acc23.y, 32);
    const float M = fmaxf(m, mo);
    const float ea = __builtin_amdgcn_exp2f(m - M);
    const float eb = __builtin_amdgcn_exp2f(mo - M);
    const float st = fmaf(s, ea, so * eb);
    const float inv = 1.0f / st;
    const f2 r01 = (acc01 * ea + o01 * eb) * inv;
    const f2 r23 = (acc23 * ea + o23 * eb) * inv;
    if (!hh) {
        const float4 bv = *(const float4*)&bias[4 * hl];
        float4 o;
        o.x = fmaxf(r01.x + bv.x, 0.0f);
        o.y = fmaxf(r01.y + bv.y, 0.0f);
        o.z = fmaxf(r23.x + bv.z, 0.0f);
        o.w = fmaxf(r23.y + bv.w, 0.0f);
        *(float4*)&out[cb] = o;
    }
}

// ======== layer-2: 8-edge compute step (unchanged from r8) ========
#define COMPUTE8(P, kk)                                                      \
    {                                                                        \
        const float t0 = logit2(P##0, xri, atv);                             \
        const float t1 = logit2(P##1, xri, atv);                             \
        const float t2 = logit2(P##2, xri, atv);                             \
        const float t3 = logit2(P##3, xri, atv);                             \
        const float t4 = logit2(P##4, xri, atv);                             \
        const float t5 = logit2(P##5, xri, atv);                             \
        const float t6 = logit2(P##6, xri, atv);                             \
        const float t7 = logit2(P##7, xri, atv);                             \
        float pA = quadtree(t0, t1, t2, t3, lane);                           \
        float pB = quadtree(t4, t5, t6, t7, lane);                           \
        pA = ((kk) + lane3 < nb4) ? pA : -1e30f;                             \
        pB = ((kk) + 4 + lane3 < nb4) ? pB : -1e30f;                         \
        float q = fmaxf(pA, pB);                                             \
        q = dpp_max<QX1>(q);                                                 \
        q = dpp_max<QX2>(q);                                                 \
        const float nm = fmaxf(m, q);                                        \
        const float sc = __builtin_amdgcn_exp2f(m - nm);                     \
        const float wA = __builtin_amdgcn_exp2f(pA - nm);                    \
        const float wB = __builtin_amdgcn_exp2f(pB - nm);                    \
        float sw = wA + wB;                                                  \
        sw = dpp_add<QX1>(sw);                                               \
        sw = dpp_add<QX2>(sw);                                               \
        s = fmaf(s, sc, sw);                                                 \
        m = nm;                                                              \
        const float w0 = dpp_mov<QB0>(wA), w1 = dpp_mov<QB1>(wA);            \
        const float w2 = dpp_mov<QB2>(wA), w3 = dpp_mov<QB3>(wA);            \
        const float w4 = dpp_mov<QB0>(wB), w5 = dpp_mov<QB1>(wB);            \
        const float w6 = dpp_mov<QB2>(wB), w7 = dpp_mov<QB3>(wB);            \
        acc = acc * sc;                                                      \
        acc += P##0 * w0;                                                    \
        acc += P##1 * w1;                                                    \
        acc += P##2 * w2;                                                    \
        acc += P##3 * w3;                                                    \
        acc += P##4 * w4;                                                    \
        acc += P##5 * w5;                                                    \
        acc += P##6 * w6;                                                    \
        acc += P##7 * w7;                                                    \
    }

#define LOAD8_2(P, kk)                                                       \
    {                                                                        \
        const int bb = ((lane & 32) + (kk)) << 2;                            \
        const int j0 = __builtin_amdgcn_ds_bpermute(bb + 0, idx);            \
        const int j1 = __builtin_amdgcn_ds_bpermute(bb + 4, idx);            \
        const int j2 = __builtin_amdgcn_ds_bpermute(bb + 8, idx);            \
        const int j3 = __builtin_amdgcn_ds_bpermute(bb + 12, idx);           \
        const int j4 = __builtin_amdgcn_ds_bpermute(bb + 16, idx);           \
        const int j5 = __builtin_amdgcn_ds_bpermute(bb + 20, idx);           \
        const int j6 = __builtin_amdgcn_ds_bpermute(bb + 24, idx);           \
        const int j7 = __builtin_amdgcn_ds_bpermute(bb + 28, idx);           \
        P##0 = *(const f2*)(xl + (((unsigned)j0) << 6) + 2 * hl);            \
        P##1 = *(const f2*)(xl + (((unsigned)j1) << 6) + 2 * hl);            \
        P##2 = *(const f2*)(xl + (((unsigned)j2) << 6) + 2 * hl);            \
        P##3 = *(const f2*)(xl + (((unsigned)j3) << 6) + 2 * hl);            \
        P##4 = *(const f2*)(xl + (((unsigned)j4) << 6) + 2 * hl);            \
        P##5 = *(const f2*)(xl + (((unsigned)j5) << 6) + 2 * hl);            \
        P##6 = *(const f2*)(xl + (((unsigned)j6) << 6) + 2 * hl);            \
        P##7 = *(const f2*)(xl + (((unsigned)j7) << 6) + 2 * hl);            \
    }

__global__ __launch_bounds__(256) void k_agg2_fc(
    const float* __restrict__ xl, const float* __restrict__ xr,
    const float* __restrict__ att, const float* __restrict__ bias,
    const int* __restrict__ ptr, const int* __restrict__ csrc,
    const float* __restrict__ Wfc, const float* __restrict__ bfc,
    float* __restrict__ out) {
    const int wid = blockIdx.x * 4 + (threadIdx.x >> 6);
    const int lane = threadIdx.x & 63;
    const int hl = lane & 31;
    const int node = wid * 2 + (lane >> 5);
    const int lane3 = lane & 3;
    const size_t nbo = (size_t)node * 64;
    const f2 xri = *(const f2*)&xr[nbo + 2 * hl];
    f2 atv = *(const f2*)&att[2 * hl];
    atv *= 1.44269504088896340736f;

    const int e0 = ptr[node];
    const int deg = ptr[node + 1] - e0;
    const int degw = max(deg, __shfl_xor(deg, 32));

    f2 A0, A1, A2, A3, A4, A5, A6, A7;
    f2 B0, B1, B2, B3, B4, B5, B6, B7;

    int nv = deg;
    int nb4 = min(nv, 32);
    int idx = 0;
    if (degw > 0) {
        const int off = max(0, min(hl, nv - 1));
        idx = csrc[min(e0 + off, N_EDGES - 1)];
        LOAD8_2(A, 0);
    }

    const f2 xs = *(const f2*)&xl[nbo + 2 * hl];
    f2 acc;
    float m, s;
    {
        float t = logit2(xs, xri, atv);
        t = dpp_add<QX1>(t);
        t = dpp_add<QX2>(t);
        t = dpp_add<RR4>(t);
        t = dpp_add<RR8>(t);
        t += __shfl_xor(t, 16);
        m = t;
        s = 1.0f;
        acc = xs;
    }

    if (degw > 0) {
        const int kw = min(32, degw);
        for (int k = 0; k < kw; k += 16) {
            const bool hasB = (k + 8 < kw);
            if (hasB) LOAD8_2(B, k + 8);
            COMPUTE8(A, k);
            if (hasB) {
                if (k + 16 < kw) LOAD8_2(A, k + 16);
                COMPUTE8(B, k + 8);
            }
        }
    }
    for (int base = 32; base < degw; base += 32) {
        nv = deg - base;
        nb4 = min(nv, 32);
        const int off = max(0, min(hl, nv - 1));
        idx = csrc[min(e0 + base + off, N_EDGES - 1)];
        LOAD8_2(A, 0);
        const int kw = min(32, degw - base);
        for (int k = 0; k < kw; k += 16) {
            const bool hasB = (k + 8 < kw);
            if (hasB) LOAD8_2(B, k + 8);
            COMPUTE8(A, k);
            if (hasB) {
                if (k + 16 < kw) LOAD8_2(A, k + 16);
                COMPUTE8(B, k + 8);
            }
        }
    }

    const float inv = 1.0f / s;
    const float v0 = fmaxf(fmaf(acc.x, inv, bias[2 * hl]), 0.0f);
    const float v1 = fmaxf(fmaf(acc.y, inv, bias[2 * hl + 1]), 0.0f);

    float res = 0.0f;
#pragma unroll
    for (int g = 0; g < 3; ++g) {
        const int cbx = 4 * g;
        const int c0 = cbx, c1 = cbx + 1;
        const int c2 = min(cbx + 2, 9), c3 = min(cbx + 3, 9);
        const float* w0r = &Wfc[(2 * hl) * 10];
        const float* w1r = &Wfc[(2 * hl + 1) * 10];
        float u0 = v0 * w0r[c0] + v1 * w1r[c0];
        float u1 = v0 * w0r[c1] + v1 * w1r[c1];
        float u2 = v0 * w0r[c2] + v1 * w1r[c2];
        float u3 = v0 * w0r[c3] + v1 * w1r[c3];
        const float t = quadtree(u0, u1, u2, u3, lane);
        if ((hl >> 2) == g) res = t;
    }
    if (hl < 10) out[(size_t)node * 10 + hl] = res + bfc[hl];
}

// ---------------- launch ----------------
static inline size_t align256(size_t x) { return (x + 255) & ~(size_t)255; }

extern "C" void kernel_launch(void* const* d_in, const int* in_sizes, int n_in,
                              void* d_out, int out_size, void* d_ws, size_t ws_size,
                              hipStream_t stream) {
    const int N = N_NODES, E = N_EDGES;
    const float* x    = (const float*)d_in[0];
    const int*   ei   = (const int*)d_in[1];
    const float* Wl1  = (const float*)d_in[2];
    const float* Wr1  = (const float*)d_in[3];
    const float* att1 = (const float*)d_in[4];
    const float* b1   = (const float*)d_in[5];
    const float* Wl2  = (const float*)d_in[6];
    const float* Wr2  = (const float*)d_in[7];
    const float* att2 = (const float*)d_in[8];
    const float* b2   = (const float*)d_in[9];
    const float* Wfc  = (const float*)d_in[10];
    const float* bfc  = (const float*)d_in[11];
    float* out = (float*)d_out;

    const int* src = ei;
    const int* dst = ei + E;

    char* base = (char*)d_ws;
    size_t off = 0;
    int* ptr  = (int*)(base + off); off = align256(off + (size_t)(N + 1) * 4);
    int* cnt  = (int*)(base + off); off = align256(off + (size_t)N * 4);
    int* bs   = (int*)(base + off); off = align256(off + 256 * 4);
    unsigned short* rank = (unsigned short*)(base + off); off = align256(off + (size_t)E * 2);
    int* csrc = (int*)(base + off); off = align256(off + (size_t)E * 4);
    unsigned short* xlb = (unsigned short*)(base + off); off = align256(off + (size_t)N * 128 * 2);
    float* xr1 = (float*)(base + off); off = align256(off + (size_t)N * 128 * 4);
    float* h1  = (float*)(base + off); off = align256(off + (size_t)N * 128 * 4);
    // layer-2 transforms reuse dead regions: xl2 over xlb (12.8MB), xr2 over xr1
    float* xl2 = (float*)xlb;
    float* xr2 = xr1;

    const int nb = (N + 255) / 256;
    const int ngb = (N + 127) / 128;

    hipMemsetAsync(cnt, 0, (size_t)N * 4, stream);
    k_hist<<<(E + 255) / 256, 256, 0, stream>>>(dst, cnt, rank, E);
    k_scan_local<<<nb, 256, 0, stream>>>(cnt, ptr, bs, N);
    k_scan_add2<<<nb, 256, 0, stream>>>(ptr, bs, N, nb, E);
    k_scatter<<<(E + 255) / 256, 256, 0, stream>>>(src, dst, ptr, rank, csrc, E);

    // layer 1: xlb = bf16(x@Wl1) [N][128], xr1 = f32 x@Wr1 [N][128]
    k_gemm_v2<true><<<dim3(ngb, 2), 256, 0, stream>>>(x, N, Wl1, Wr1, (float*)xlb, xr1);
    k_agg1<<<(N + 3) / 4, 256, 0, stream>>>(xlb, xr1, att1, b1, ptr, csrc, h1);
    // layer 2: f32 [N][64] x2
    k_gemm_v2<false><<<dim3(ngb, 1), 256, 0, stream>>>(h1, N, Wl2, Wr2, xl2, xr2);
    k_agg2_fc<<<(N / 2 + 3) / 4, 256, 0, stream>>>(xl2, xr2, att2, b2, ptr, csrc, Wfc, bfc, out);
}